// Round 13
// baseline (56.356 us; speedup 1.0000x reference)
//
#include <hip/hip_runtime.h>
#include <hip/hip_bf16.h>
#include <math.h>

#define NUM_GRAPHS 512
#define D 128
#define SLOTS 16               // register row-slots per thread
#define RG 16                  // row-groups per half (256 threads / 16 lanes-per-row)
#define CAPR (RG * SLOTS)      // 256 rows register capacity per (segment,modality)

__device__ inline int lower_bound_i(const int* __restrict__ b, int n, int v) {
    int lo = 0, hi = n;
    while (lo < hi) {
        int mid = (lo + hi) >> 1;
        if (b[mid] < v) lo = mid + 1; else hi = mid;
    }
    return lo;
}

__device__ inline void add4(float4& a, const float4 v) {
    a.x += v.x; a.y += v.y; a.z += v.z; a.w += v.w;
}

__device__ inline unsigned int pkbf(float a, float b) {   // v_cvt_pk_bf16_f32
    __hip_bfloat162 h = __float22bfloat162_rn(make_float2(a, b));
    return *reinterpret_cast<unsigned int*>(&h);
}

// One block per segment s, 512 threads; half (t>>8) = modality.
// REGISTER-staged single pass (R12 lesson: LDS staging kept VGPR=64, loads
// serialized, and 70KB LDS capped residency; the second z-touch must be free).
// Thread (rg = tt>>4, li = tt&15): owns dims [8*li, 8*li+8) of rows
// start+rg+16k, k<16, stored bf16-packed in 16 uint4 slots (64 VGPRs).
// Phase A: 32 guarded float4 loads -> distinct slot regs (real MLP) + fp32 acc.
// Phase B: LDS tree-reduce per-dim, norm scalars (raw g + epilogue inv fold).
// Phase C: dots from REGISTERS, 4-level shfl_xor within 16-lane row groups.
// Overflow rows (cnt>256, ~never) via global fallback for sum and dots.
__global__ __launch_bounds__(512)
__attribute__((amdgpu_waves_per_eu(4, 4)))
void fused_gcl(
    const float* __restrict__ z1, const float* __restrict__ z2,
    const int* __restrict__ b1, const int* __restrict__ b2,
    float* __restrict__ dsq, int N)
{
    const int s    = blockIdx.x;
    const int t    = threadIdx.x;
    const int half = t >> 8;     // 0: z1/b1, 1: z2/b2
    const int tt   = t & 255;
    const int rg   = tt >> 4;    // row-group 0..15
    const int li   = tt & 15;    // lane-in-row 0..15 (dims 8*li..8*li+7)

    const float* z = half ? z2 : z1;
    const int*   b = half ? b2 : b1;

    __shared__ int   bnds[2][2];
    __shared__ float part[2][RG][D];   // 16 KB: per-row-group partial sums
    __shared__ float gbuf[2][D];       // raw segment sums
    __shared__ float ssred[2][2];
    __shared__ float invsh[2];
    __shared__ float warr[2][4];

    if (tt < 2) bnds[half][tt] = lower_bound_i(b, N, s + tt);
    __syncthreads();
    const int start = bnds[half][0], end = bnds[half][1];

    // ---- Phase A: one global pass -> register slots + fp32 accumulators ----
    uint4 st[SLOTS];
    float4 accA = make_float4(0.f, 0.f, 0.f, 0.f), accB = accA;
    const float4* Z = reinterpret_cast<const float4*>(z);
#pragma unroll
    for (int k = 0; k < SLOTS; ++k) {
        const int row = start + rg + k * RG;
        uint4 sv = make_uint4(0u, 0u, 0u, 0u);
        if (row < end) {
            const float4 va = Z[(size_t)row * 32 + 2 * li];
            const float4 vb = Z[(size_t)row * 32 + 2 * li + 1];
            add4(accA, va); add4(accB, vb);
            sv.x = pkbf(va.x, va.y); sv.y = pkbf(va.z, va.w);
            sv.z = pkbf(vb.x, vb.y); sv.w = pkbf(vb.z, vb.w);
        }
        st[k] = sv;
    }
    // overflow rows: accumulate only (dots read them back from L2/L3 later)
    for (int row = start + CAPR + rg; row < end; row += RG) {
        add4(accA, Z[(size_t)row * 32 + 2 * li]);
        add4(accB, Z[(size_t)row * 32 + 2 * li + 1]);
    }
    {
        float4* pp = reinterpret_cast<float4*>(&part[half][rg][8 * li]);
        pp[0] = accA; pp[1] = accB;
    }
    __syncthreads();

    // ---- Phase B: per-dim tree reduce + norm scalar ----
    if (tt < D) {
        float gsum = 0.f;
#pragma unroll
        for (int j = 0; j < RG; ++j) gsum += part[half][j][tt];
        gbuf[half][tt] = gsum;
        float sq = gsum * gsum;
#pragma unroll
        for (int m = 1; m <= 32; m <<= 1) sq += __shfl_xor(sq, m, 64);
        if ((tt & 63) == 0) ssred[half][tt >> 6] = sq;
    }
    __syncthreads();
    if (tt == 0)
        invsh[half] = 1.0f / fmaxf(sqrtf(ssred[half][0] + ssred[half][1]), 1e-12f);
    __syncthreads();
    const float invP = invsh[half];
    const float invC = invsh[half ^ 1];

    // this thread's 8-dim fragments of raw g (own + cross)
    const float4 gpA = reinterpret_cast<const float4*>(&gbuf[half][8 * li])[0];
    const float4 gpB = reinterpret_cast<const float4*>(&gbuf[half][8 * li])[1];
    const float4 gcA = reinterpret_cast<const float4*>(&gbuf[half ^ 1][8 * li])[0];
    const float4 gcB = reinterpret_cast<const float4*>(&gbuf[half ^ 1][8 * li])[1];

    // ---- Phase C: dots + JSD straight from registers ----
    float acc = 0.f;
#pragma unroll
    for (int k = 0; k < SLOTS; ++k) {
        const uint4 u = st[k];
        const float f0 = __uint_as_float(u.x << 16);
        const float f1 = __uint_as_float(u.x & 0xffff0000u);
        const float f2 = __uint_as_float(u.y << 16);
        const float f3 = __uint_as_float(u.y & 0xffff0000u);
        const float f4 = __uint_as_float(u.z << 16);
        const float f5 = __uint_as_float(u.z & 0xffff0000u);
        const float f6 = __uint_as_float(u.w << 16);
        const float f7 = __uint_as_float(u.w & 0xffff0000u);
        float p  = f0*gpA.x + f1*gpA.y + f2*gpA.z + f3*gpA.w
                 + f4*gpB.x + f5*gpB.y + f6*gpB.z + f7*gpB.w;
        float cr = f0*gcA.x + f1*gcA.y + f2*gcA.z + f3*gcA.w
                 + f4*gcB.x + f5*gcB.y + f6*gcB.z + f7*gcB.w;
        float sv = f0*f0 + f1*f1 + f2*f2 + f3*f3 + f4*f4 + f5*f5 + f6*f6 + f7*f7;
        p  += __shfl_xor(p, 1, 64);  p  += __shfl_xor(p, 2, 64);
        p  += __shfl_xor(p, 4, 64);  p  += __shfl_xor(p, 8, 64);
        cr += __shfl_xor(cr, 1, 64); cr += __shfl_xor(cr, 2, 64);
        cr += __shfl_xor(cr, 4, 64); cr += __shfl_xor(cr, 8, 64);
        sv += __shfl_xor(sv, 1, 64); sv += __shfl_xor(sv, 2, 64);
        sv += __shfl_xor(sv, 4, 64); sv += __shfl_xor(sv, 8, 64);
        if (li == 0) {
            const float invz  = 1.0f / fmaxf(sqrtf(sv), 1e-12f);
            const float pos   = p  * invP * invz;
            const float cross = cr * invC * invz;
            const float d = log1pf(__expf(-cross)) - log1pf(__expf(-pos));
            acc += d * d;    // zero-filled slots give d == 0
        }
    }
    // overflow rows: exact fp32 from global (L2/L3-resident; ~never taken)
    for (int row = start + CAPR + rg; row < end; row += RG) {
        const float4 va = Z[(size_t)row * 32 + 2 * li];
        const float4 vb = Z[(size_t)row * 32 + 2 * li + 1];
        float p  = va.x*gpA.x + va.y*gpA.y + va.z*gpA.z + va.w*gpA.w
                 + vb.x*gpB.x + vb.y*gpB.y + vb.z*gpB.z + vb.w*gpB.w;
        float cr = va.x*gcA.x + va.y*gcA.y + va.z*gcA.z + va.w*gcA.w
                 + vb.x*gcB.x + vb.y*gcB.y + vb.z*gcB.z + vb.w*gcB.w;
        float sv = va.x*va.x + va.y*va.y + va.z*va.z + va.w*va.w
                 + vb.x*vb.x + vb.y*vb.y + vb.z*vb.z + vb.w*vb.w;
        p  += __shfl_xor(p, 1, 64);  p  += __shfl_xor(p, 2, 64);
        p  += __shfl_xor(p, 4, 64);  p  += __shfl_xor(p, 8, 64);
        cr += __shfl_xor(cr, 1, 64); cr += __shfl_xor(cr, 2, 64);
        cr += __shfl_xor(cr, 4, 64); cr += __shfl_xor(cr, 8, 64);
        sv += __shfl_xor(sv, 1, 64); sv += __shfl_xor(sv, 2, 64);
        sv += __shfl_xor(sv, 4, 64); sv += __shfl_xor(sv, 8, 64);
        if (li == 0) {
            const float invz  = 1.0f / fmaxf(sqrtf(sv), 1e-12f);
            const float pos   = p  * invP * invz;
            const float cross = cr * invC * invz;
            const float d = log1pf(__expf(-cross)) - log1pf(__expf(-pos));
            acc += d * d;
        }
    }

    // ---- block reduction of d^2 sums ----
#pragma unroll
    for (int m = 1; m <= 32; m <<= 1) acc += __shfl_xor(acc, m, 64);
    if ((tt & 63) == 0) warr[half][tt >> 6] = acc;
    __syncthreads();
    if (tt == 0)
        dsq[half * NUM_GRAPHS + s] = warr[half][0] + warr[half][1]
                                   + warr[half][2] + warr[half][3];
}

// Single block, 1024 threads: dsq[0..511] -> s0, dsq[512..1023] -> s1.
__global__ __launch_bounds__(1024) void finalize_kernel(const float* __restrict__ dsq,
                                                        float* __restrict__ out) {
    const int t = threadIdx.x;
    float v = dsq[t];
#pragma unroll
    for (int m = 1; m <= 32; m <<= 1) v += __shfl_xor(v, m, 64);
    __shared__ float w[16];
    if ((t & 63) == 0) w[t >> 6] = v;
    __syncthreads();
    if (t == 0) {
        float s0 = 0.f, s1 = 0.f;
#pragma unroll
        for (int i = 0; i < 8; ++i)  s0 += w[i];
#pragma unroll
        for (int i = 8; i < 16; ++i) s1 += w[i];
        out[0] = sqrtf(s0) + sqrtf(s1);
    }
}

extern "C" void kernel_launch(void* const* d_in, const int* in_sizes, int n_in,
                              void* d_out, int out_size, void* d_ws, size_t ws_size,
                              hipStream_t stream) {
    const float* z1 = (const float*)d_in[0];
    const float* z2 = (const float*)d_in[1];
    const int*   b1 = (const int*)d_in[2];
    const int*   b2 = (const int*)d_in[3];
    const int N = in_sizes[2];

    float* dsq = (float*)d_ws;   // 1024 floats, fully written every call

    fused_gcl<<<NUM_GRAPHS, 512, 0, stream>>>(z1, z2, b1, b2, dsq, N);
    finalize_kernel<<<1, 1024, 0, stream>>>(dsq, (float*)d_out);
}

// Round 14
// 37.825 us; speedup vs baseline: 1.4899x; 1.4899x over previous
//
#include <hip/hip_runtime.h>
#include <math.h>

#define NUM_GRAPHS 512
#define D 128
#define CAP 168      // staged rows per (segment,modality); 2*CAP*128B + 9.7KB static -> 3 blocks/CU
#define ROWB 128     // bytes per staged fp8 row (128 * 1B)

typedef float floatx2 __attribute__((ext_vector_type(2)));

__device__ inline int lower_bound_i(const int* __restrict__ b, int n, int v) {
    int lo = 0, hi = n;
    while (lo < hi) {
        int mid = (lo + hi) >> 1;
        if (b[mid] < v) lo = mid + 1; else hi = mid;
    }
    return lo;
}

__device__ inline void add4(float4& a, const float4 v) {
    a.x += v.x; a.y += v.y; a.z += v.z; a.w += v.w;
}

// Stage one float4 (fp32 dims 4c..4c+3 of row idx) as 4B of OCP-e4m3 fp8 into
// LDS via v_cvt_pk_fp8_f32. 16B-chunk XOR swizzle (^ idx&7) spreads banks.
__device__ inline void stage(unsigned char* zb, int idx, int c, float4 v) {
    if (idx >= CAP) return;
    int r = __builtin_amdgcn_cvt_pk_fp8_f32(v.x, v.y, 0, false);   // bytes 0,1
    r     = __builtin_amdgcn_cvt_pk_fp8_f32(v.z, v.w, r, true);    // bytes 2,3
    const int sc = (c >> 2) ^ (idx & 7);
    *reinterpret_cast<unsigned int*>(zb + (size_t)idx * ROWB + sc * 16 + (c & 3) * 4)
        = (unsigned int)r;
}

// One block per segment s, 512 threads; half (t>>8) = modality.
// Phase A: single HBM pass: fp32 segment-sum (exact) + fp8 LDS copy of first
//   CAP rows. fp8 (vs R10 bf16) halves the staged footprint: 52.7KB/block ->
//   3 blocks/CU = 24 waves (+50% latency hiding) AND coverage 70%->86%.
// Phase B: normalize g. Phase C: quad-per-row dots + JSD; staged rows decoded
//   with v_cvt_pk_f32_fp8 (e4m3 noise ~3%/row, random sign -> <<0.1% on the
//   final scalar; threshold is 2%); overflow rows from global (L2/L3-resident).
__global__ __launch_bounds__(512) void fused_gcl(
    const float* __restrict__ z1, const float* __restrict__ z2,
    const int* __restrict__ b1, const int* __restrict__ b2,
    float* __restrict__ dsq, int N)
{
    extern __shared__ unsigned char smem[];    // 2 * CAP * ROWB bytes
    const int s    = blockIdx.x;
    const int t    = threadIdx.x;
    const int half = t >> 8;     // 0: z1/b1, 1: z2/b2
    const int tt   = t & 255;

    const float* z = half ? z2 : z1;
    const int*   b = half ? b2 : b1;
    unsigned char* zb = smem + (size_t)half * CAP * ROWB;

    __shared__ int    bnds[2][2];
    __shared__ float4 part[2][8][32];
    __shared__ float  gbuf[2][D];
    __shared__ float  warr[2][4];

    if (tt < 2) bnds[half][tt] = lower_bound_i(b, N, s + tt);
    __syncthreads();
    const int start = bnds[half][0], end = bnds[half][1];
    const int cnt    = end - start;
    const int staged = cnt < CAP ? cnt : CAP;

    // ---- Phase A: single pass: fp32 sum + fp8 stage ----
    {
        const int r = tt >> 5;   // 0..7
        const int c = tt & 31;   // float4 col
        const float4* Z = reinterpret_cast<const float4*>(z);
        float4 a0 = make_float4(0.f, 0.f, 0.f, 0.f), a1 = a0, a2 = a0, a3 = a0;
        int row = start + r;
        for (; row + 24 < end; row += 32) {
            float4 v0 = Z[(size_t)row * 32 + c];
            float4 v1 = Z[(size_t)(row + 8)  * 32 + c];
            float4 v2 = Z[(size_t)(row + 16) * 32 + c];
            float4 v3 = Z[(size_t)(row + 24) * 32 + c];
            add4(a0, v0); stage(zb, row - start,      c, v0);
            add4(a1, v1); stage(zb, row - start + 8,  c, v1);
            add4(a2, v2); stage(zb, row - start + 16, c, v2);
            add4(a3, v3); stage(zb, row - start + 24, c, v3);
        }
        for (; row < end; row += 8) {
            float4 v = Z[(size_t)row * 32 + c];
            add4(a0, v);
            stage(zb, row - start, c, v);
        }
        add4(a0, a1); add4(a2, a3); add4(a0, a2);
        part[half][r][c] = a0;
    }
    __syncthreads();

    // ---- Phase B: reduce + normalize g into gbuf[half] ----
    if (tt < 32) {
        float4 sum = part[half][0][tt];
#pragma unroll
        for (int g = 1; g < 8; ++g) add4(sum, part[half][g][tt]);
        float ss = sum.x * sum.x + sum.y * sum.y + sum.z * sum.z + sum.w * sum.w;
#pragma unroll
        for (int m = 1; m <= 16; m <<= 1) ss += __shfl_xor(ss, m, 64);
        const float inv = 1.0f / fmaxf(sqrtf(ss), 1e-12f);
        sum.x *= inv; sum.y *= inv; sum.z *= inv; sum.w *= inv;
        reinterpret_cast<float4*>(gbuf[half])[tt] = sum;
    }
    __syncthreads();

    // ---- Phase C: quad-per-row dots + JSD ----
    const int q   = tt & 3;    // quarter of row: dims 32q..32q+31
    const int rid = tt >> 2;   // 0..63
    float4 gpv[8], gcv[8];
    {
        const float4* GP = reinterpret_cast<const float4*>(gbuf[half])     + q * 8;
        const float4* GC = reinterpret_cast<const float4*>(gbuf[half ^ 1]) + q * 8;
#pragma unroll
        for (int i = 0; i < 8; ++i) { gpv[i] = GP[i]; gcv[i] = GC[i]; }
    }

    float acc = 0.f;
    // staged rows: fp8 from LDS (chunks 2q, 2q+1 hold dims 32q..32q+31)
    for (int idx = rid; idx < staged; idx += 64) {
        const unsigned char* rowp = zb + (size_t)idx * ROWB;
        const int x = idx & 7;
        float p = 0.f, cr = 0.f, ssv = 0.f;
#pragma unroll
        for (int j2 = 0; j2 < 2; ++j2) {
            const int sc = (2 * q + j2) ^ x;
            const uint4 u = *reinterpret_cast<const uint4*>(rowp + sc * 16);
#pragma unroll
            for (int bb = 0; bb < 4; ++bb) {
                const unsigned int ub = bb == 0 ? u.x : bb == 1 ? u.y : bb == 2 ? u.z : u.w;
                const floatx2 lo = __builtin_amdgcn_cvt_pk_f32_fp8(ub, false);
                const floatx2 hi = __builtin_amdgcn_cvt_pk_f32_fp8(ub, true);
                const float4 gp = gpv[4 * j2 + bb];
                const float4 hc = gcv[4 * j2 + bb];
                p   += lo.x * gp.x + lo.y * gp.y + hi.x * gp.z + hi.y * gp.w;
                cr  += lo.x * hc.x + lo.y * hc.y + hi.x * hc.z + hi.y * hc.w;
                ssv += lo.x * lo.x + lo.y * lo.y + hi.x * hi.x + hi.y * hi.y;
            }
        }
        p   += __shfl_xor(p, 1, 64);   p   += __shfl_xor(p, 2, 64);
        cr  += __shfl_xor(cr, 1, 64);  cr  += __shfl_xor(cr, 2, 64);
        ssv += __shfl_xor(ssv, 1, 64); ssv += __shfl_xor(ssv, 2, 64);
        if (q == 0) {
            const float invz  = 1.0f / fmaxf(sqrtf(ssv), 1e-12f);
            const float pos   = p  * invz;
            const float cross = cr * invz;
            const float d = log1pf(__expf(-cross)) - log1pf(__expf(-pos));
            acc += d * d;
        }
    }
    // un-staged rows: exact fp32 from global (L2/L3-resident — just streamed in A)
    for (int idx = staged + rid; idx < cnt; idx += 64) {
        const int row = start + idx;
        const float4* Z = reinterpret_cast<const float4*>(z);
        float p = 0.f, cr = 0.f, ssv = 0.f;
#pragma unroll
        for (int i = 0; i < 8; ++i) {
            float4 zv = Z[(size_t)row * 32 + q * 8 + i];
            p   += zv.x * gpv[i].x + zv.y * gpv[i].y + zv.z * gpv[i].z + zv.w * gpv[i].w;
            cr  += zv.x * gcv[i].x + zv.y * gcv[i].y + zv.z * gcv[i].z + zv.w * gcv[i].w;
            ssv += zv.x * zv.x + zv.y * zv.y + zv.z * zv.z + zv.w * zv.w;
        }
        p   += __shfl_xor(p, 1, 64);   p   += __shfl_xor(p, 2, 64);
        cr  += __shfl_xor(cr, 1, 64);  cr  += __shfl_xor(cr, 2, 64);
        ssv += __shfl_xor(ssv, 1, 64); ssv += __shfl_xor(ssv, 2, 64);
        if (q == 0) {
            const float invz  = 1.0f / fmaxf(sqrtf(ssv), 1e-12f);
            const float pos   = p  * invz;
            const float cross = cr * invz;
            const float d = log1pf(__expf(-cross)) - log1pf(__expf(-pos));
            acc += d * d;
        }
    }

#pragma unroll
    for (int m = 1; m <= 32; m <<= 1) acc += __shfl_xor(acc, m, 64);
    if ((tt & 63) == 0) warr[half][tt >> 6] = acc;
    __syncthreads();
    if (tt == 0)
        dsq[half * NUM_GRAPHS + s] = warr[half][0] + warr[half][1]
                                   + warr[half][2] + warr[half][3];
}

// Single block, 1024 threads: dsq[0..511] -> s0, dsq[512..1023] -> s1.
__global__ __launch_bounds__(1024) void finalize_kernel(const float* __restrict__ dsq,
                                                        float* __restrict__ out) {
    const int t = threadIdx.x;
    float v = dsq[t];
#pragma unroll
    for (int m = 1; m <= 32; m <<= 1) v += __shfl_xor(v, m, 64);
    __shared__ float w[16];
    if ((t & 63) == 0) w[t >> 6] = v;
    __syncthreads();
    if (t == 0) {
        float s0 = 0.f, s1 = 0.f;
#pragma unroll
        for (int i = 0; i < 8; ++i)  s0 += w[i];
#pragma unroll
        for (int i = 8; i < 16; ++i) s1 += w[i];
        out[0] = sqrtf(s0) + sqrtf(s1);
    }
}

extern "C" void kernel_launch(void* const* d_in, const int* in_sizes, int n_in,
                              void* d_out, int out_size, void* d_ws, size_t ws_size,
                              hipStream_t stream) {
    const float* z1 = (const float*)d_in[0];
    const float* z2 = (const float*)d_in[1];
    const int*   b1 = (const int*)d_in[2];
    const int*   b2 = (const int*)d_in[3];
    const int N = in_sizes[2];

    float* dsq = (float*)d_ws;   // 1024 floats, fully written every call

    const int smem_bytes = 2 * CAP * ROWB;   // 43008 B dynamic (+ ~9.7 KB static)
    (void)hipFuncSetAttribute((const void*)fused_gcl,
                              hipFuncAttributeMaxDynamicSharedMemorySize, smem_bytes);

    fused_gcl<<<NUM_GRAPHS, 512, smem_bytes, stream>>>(z1, z2, b1, b2, dsq, N);
    finalize_kernel<<<1, 1024, 0, stream>>>(dsq, (float*)d_out);
}